// Round 5
// baseline (224.413 us; speedup 1.0000x reference)
//
#include <hip/hip_runtime.h>
#include <math.h>

#define EPSF 1e-6f

typedef float v4f __attribute__((ext_vector_type(4)));
typedef int   v2i __attribute__((ext_vector_type(2)));

struct F3   { float x, y, z; };
struct Quat { float x, y, z, w; };
struct Sim3 { F3 t; Quat q; float s; };

__device__ __forceinline__ F3 cross3(F3 a, F3 b) {
    return { a.y*b.z - a.z*b.y, a.z*b.x - a.x*b.z, a.x*b.y - a.y*b.x };
}

__device__ __forceinline__ F3 quat_rotate(Quat q, F3 v) {
    F3 qv { q.x, q.y, q.z };
    F3 uv  = cross3(qv, v);
    F3 cuv = cross3(qv, uv);
    return { v.x + 2.0f*(q.w*uv.x + cuv.x),
             v.y + 2.0f*(q.w*uv.y + cuv.y),
             v.z + 2.0f*(q.w*uv.z + cuv.z) };
}

__device__ __forceinline__ Quat quat_mul(Quat a, Quat b) {
    return {
        a.w*b.x + a.x*b.w + a.y*b.z - a.z*b.y,
        a.w*b.y - a.x*b.z + a.y*b.w + a.z*b.x,
        a.w*b.z + a.x*b.y - a.y*b.x + a.z*b.w,
        a.w*b.w - a.x*b.x - a.y*b.y - a.z*b.z
    };
}

__device__ __forceinline__ Sim3 sim3_inv(Sim3 T) {
    Quat qi { -T.q.x, -T.q.y, -T.q.z, T.q.w };
    float si = __fdividef(1.0f, T.s);
    F3 r = quat_rotate(qi, T.t);
    return { { -si*r.x, -si*r.y, -si*r.z }, qi, si };
}

__device__ __forceinline__ Sim3 sim3_mul(Sim3 A, Sim3 B) {
    F3 r = quat_rotate(A.q, B.t);
    return { { A.t.x + A.s*r.x, A.t.y + A.s*r.y, A.t.z + A.s*r.z },
             quat_mul(A.q, B.q), A.s * B.s };
}

// rows are 8 floats = 32 B, base 256-B aligned -> v4f-safe
__device__ __forceinline__ Sim3 load_sim3(const float* __restrict__ p) {
    v4f a = *reinterpret_cast<const v4f*>(p);
    v4f b = *reinterpret_cast<const v4f*>(p + 4);
    return { {a.x, a.y, a.z}, {a.w, b.x, b.y, b.z}, b.w };
}

// nontemporal loads for one-shot streams (keeps L2/L3 room for Twc gathers)
__device__ __forceinline__ Sim3 load_sim3_nt(const float* __restrict__ p) {
    v4f a = __builtin_nontemporal_load(reinterpret_cast<const v4f*>(p));
    v4f b = __builtin_nontemporal_load(reinterpret_cast<const v4f*>(p) + 1);
    return { {a.x, a.y, a.z}, {a.w, b.x, b.y, b.z}, b.w };
}

// atan2 for y >= 0 -> [0, pi].  A&S 4.4.49 polynomial, |err| <= 1e-5 rad.
__device__ __forceinline__ float fast_atan2_pos(float y, float x) {
    float ax = fabsf(x);
    float mn = fminf(y, ax);
    float mx = fmaxf(y, ax);
    float t  = __fdividef(mn, mx);
    float s  = t * t;
    float p  = fmaf(s, 0.0208351f, -0.0851330f);
    p = fmaf(s, p,  0.1801410f);
    p = fmaf(s, p, -0.3302995f);
    p = fmaf(s, p,  0.9998660f);
    float r = t * p;
    r = (y > ax)   ? (1.5707963268f - r) : r;
    r = (x < 0.0f) ? (3.1415926536f - r) : r;
    return r;
}

// out[0..2]=tau, out[3..5]=phi, out[6]=sigma — mirrors the jax reference
// branch-for-branch; generic A,B,C path under a wave-uniform branch
// (fallbacks ~never taken for this data).  f32 Cramer + 1 refinement step
// (verified round 4: absmax 0.5 vs 4.88 threshold).
__device__ __forceinline__ void sim3_log(Sim3 T, float out[7]) {
    float qx = T.q.x, qy = T.q.y, qz = T.q.z, qw = T.q.w;
    float nv = sqrtf(qx*qx + qy*qy + qz*qz);
    float theta_r = 2.0f * fast_atan2_pos(nv, qw);
    bool  nv_small = nv < EPSF;
    float fac = nv_small ? 2.0f : __fdividef(theta_r, nv);
    float px = fac*qx, py = fac*qy, pz = fac*qz;
    float sigma = __logf(T.s);
    float theta = nv_small ? 2.0f*nv : theta_r;

    bool sig_small = fabsf(sigma) < EPSF;
    bool th_small  = theta < EPSF;
    float scale = __expf(sigma);
    float A, B, C;
    if (!sig_small && !th_small) {
        float th = theta, sg = sigma;
        float th2 = th*th, sg2 = sg*sg;
        C = __fdividef(scale - 1.0f, sg);
        float sth = __sinf(th), cth = __cosf(th);
        float a = scale * sth;
        float b = scale * cth;
        float c = th2 + sg2;
        float rc = __fdividef(1.0f, c);
        A = __fdividef(fmaf(a, sg, (1.0f - b)*th), th * c);
        B = __fdividef(C - fmaf(b - 1.0f, sg, a*th) * rc, th2);
    } else {
        float sg = sig_small ? 1.0f : sigma;
        float th = th_small  ? 1.0f : theta;
        float th2 = th*th, sg2 = sg*sg;
        C = sig_small ? 1.0f : __fdividef(scale - 1.0f, sg);
        float sth = __sinf(th), cth = __cosf(th);
        float A_ss = th_small ? 0.5f : __fdividef(1.0f - cth, th2);
        float B_ss = th_small ? (1.0f/6.0f) : __fdividef(th - sth, th2 * th);
        float a = scale * sth;
        float b = scale * cth;
        float c = th2 + sg2;
        float rc = __fdividef(1.0f, c);
        float A_g = __fdividef(fmaf(a, sg, (1.0f - b)*th), th * c);
        float B_g = __fdividef(C - fmaf(b - 1.0f, sg, a*th) * rc, th2);
        float A_ts = __fdividef(fmaf(sg - 1.0f, scale, 1.0f), sg2);
        float B_ts = __fdividef(fmaf(scale, fmaf(sg, sg - 2.0f, 2.0f), -2.0f), 2.0f*sg2*sg);
        A = sig_small ? A_ss : (th_small ? A_ts : A_g);
        B = sig_small ? B_ss : (th_small ? B_ts : B_g);
    }

    float P01 = -pz, P02 =  py;
    float P10 =  pz, P12 = -px;
    float P20 = -py, P21 =  px;
    float Q00 = P01*P10 + P02*P20;
    float Q01 = P02*P21;
    float Q02 = P01*P12;
    float Q10 = P12*P20;
    float Q11 = P10*P01 + P12*P21;
    float Q12 = P10*P02;
    float Q20 = P21*P10;
    float Q21 = P20*P01;
    float Q22 = P20*P02 + P21*P12;

    float W00 = C + B*Q00,          W01 = A*P01 + B*Q01, W02 = A*P02 + B*Q02;
    float W10 = A*P10 + B*Q10,      W11 = C + B*Q11,     W12 = A*P12 + B*Q12;
    float W20 = A*P20 + B*Q20,      W21 = A*P21 + B*Q21, W22 = C + B*Q22;

    float c00 = fmaf(W11, W22, -W12*W21);
    float c01 = fmaf(W12, W20, -W10*W22);
    float c02 = fmaf(W10, W21, -W11*W20);
    float a01 = fmaf(W02, W21, -W01*W22);
    float a02 = fmaf(W01, W12, -W02*W11);
    float a11 = fmaf(W00, W22, -W02*W20);
    float a12 = fmaf(W02, W10, -W00*W12);
    float a21 = fmaf(W01, W20, -W00*W21);
    float a22 = fmaf(W00, W11, -W01*W10);
    float det = fmaf(W00, c00, fmaf(W01, c01, W02*c02));
    float idet = __fdividef(1.0f, det);
    float tx = T.t.x, ty = T.t.y, tz = T.t.z;
    float t0 = fmaf(c00, tx, fmaf(a01, ty, a02*tz)) * idet;
    float t1 = fmaf(c01, tx, fmaf(a11, ty, a12*tz)) * idet;
    float t2 = fmaf(c02, tx, fmaf(a21, ty, a22*tz)) * idet;
    float r0 = tx - fmaf(W00, t0, fmaf(W01, t1, W02*t2));
    float r1 = ty - fmaf(W10, t0, fmaf(W11, t1, W12*t2));
    float r2 = tz - fmaf(W20, t0, fmaf(W21, t1, W22*t2));
    t0 = fmaf(fmaf(c00, r0, fmaf(a01, r1, a02*r2)), idet, t0);
    t1 = fmaf(fmaf(c01, r0, fmaf(a11, r1, a12*r2)), idet, t1);
    t2 = fmaf(fmaf(c02, r0, fmaf(a21, r1, a22*r2)), idet, t2);

    out[0] = t0; out[1] = t1; out[2] = t2;
    out[3] = px; out[4] = py; out[5] = pz; out[6] = sigma;
}

// one item's full residual, given pre-loaded state
__device__ __forceinline__ void compute_item(
        Sim3 Ti, Sim3 Tj, Sim3 Tp, Sim3 To,
        Sim3 Ga, Sim3 Gb, Sim3 Tl,
        const float pwv[7], const float owv[7],
        float res[7]) {
    Sim3 delta = sim3_mul(sim3_inv(Ti), Tj);
    float r[7];
    sim3_log(sim3_mul(delta, Tp), r);
    #pragma unroll
    for (int k = 0; k < 7; ++k) res[k] = r[k] * pwv[k];
    sim3_log(sim3_mul(delta, To), r);
    #pragma unroll
    for (int k = 0; k < 7; ++k) res[k] = fmaf(r[k], owv[k], res[k]);
    sim3_log(sim3_mul(sim3_mul(sim3_inv(Ga), Gb), Tl), r);
    #pragma unroll
    for (int k = 0; k < 7; ++k) res[k] += r[k];
}

// 2 items per thread (rows i and i+half): doubles in-flight loads per wave
// so item-1's HBM latency hides under item-0's ~4k-cycle compute chain.
// Round-4 counters showed latency-bound (VALUBusy 35%, HBM 52%, dur 71us
// vs 38us BW floor) -- per-wave MLP is the lever, not VALU count.
__global__ void __launch_bounds__(256) pgo_kernel(
        const float* __restrict__ Twc,
        const float* __restrict__ Tp_inv,
        const float* __restrict__ To_inv,
        const float* __restrict__ pw,
        const float* __restrict__ ow,
        const int*   __restrict__ edges,
        const float* __restrict__ T_lc,
        float*       __restrict__ out,
        int n, int half) {
    int i0 = blockIdx.x * blockDim.x + threadIdx.x;
    if (i0 >= half) return;
    int i1 = i0 + half;
    bool has1 = i1 < n;
    int i1c = has1 ? i1 : i0;          // clamped: loads always in-bounds
    size_t a8 = (size_t)i0  * 8, a7 = (size_t)i0  * 7;
    size_t b8 = (size_t)i1c * 8, b7 = (size_t)i1c * 7;

    // ---- issue ALL loads for both items upfront (~28 vector loads):
    // gathers first (longest latency), then streams ----
    v2i e0 = __builtin_nontemporal_load(
                 reinterpret_cast<const v2i*>(edges + 2*(size_t)i0));
    v2i e1 = __builtin_nontemporal_load(
                 reinterpret_cast<const v2i*>(edges + 2*(size_t)i1c));
    Sim3 Ga0 = load_sim3(Twc + (size_t)e0.x * 8);
    Sim3 Gb0 = load_sim3(Twc + (size_t)e0.y * 8);
    Sim3 Ga1 = load_sim3(Twc + (size_t)e1.x * 8);
    Sim3 Gb1 = load_sim3(Twc + (size_t)e1.y * 8);
    Sim3 Tl0 = load_sim3_nt(T_lc + a8);
    Sim3 Tl1 = load_sim3_nt(T_lc + b8);
    Sim3 Ti0 = load_sim3(Twc + a8);
    Sim3 Tj0 = load_sim3(Twc + a8 + 8);
    Sim3 Ti1 = load_sim3(Twc + b8);
    Sim3 Tj1 = load_sim3(Twc + b8 + 8);
    Sim3 Tp0 = load_sim3_nt(Tp_inv + a8);
    Sim3 Tp1 = load_sim3_nt(Tp_inv + b8);
    Sim3 To0 = load_sim3_nt(To_inv + a8);
    Sim3 To1 = load_sim3_nt(To_inv + b8);
    float pw0[7], ow0[7], pw1[7], ow1[7];
    #pragma unroll
    for (int k = 0; k < 7; ++k) {
        pw0[k] = __builtin_nontemporal_load(pw + a7 + k);
        ow0[k] = __builtin_nontemporal_load(ow + a7 + k);
        pw1[k] = __builtin_nontemporal_load(pw + b7 + k);
        ow1[k] = __builtin_nontemporal_load(ow + b7 + k);
    }

    // ---- item 0: its compute chain covers item 1's load latency ----
    float res[7];
    compute_item(Ti0, Tj0, Tp0, To0, Ga0, Gb0, Tl0, pw0, ow0, res);
    #pragma unroll
    for (int k = 0; k < 7; ++k) out[a7 + k] = res[k];

    // ---- item 1 (loads long since landed) ----
    if (has1) {
        compute_item(Ti1, Tj1, Tp1, To1, Ga1, Gb1, Tl1, pw1, ow1, res);
        #pragma unroll
        for (int k = 0; k < 7; ++k) out[b7 + k] = res[k];
    }
}

extern "C" void kernel_launch(void* const* d_in, const int* in_sizes, int n_in,
                              void* d_out, int out_size, void* d_ws, size_t ws_size,
                              hipStream_t stream) {
    const float* Twc   = (const float*)d_in[0];
    const float* Tp    = (const float*)d_in[1];
    const float* To    = (const float*)d_in[2];
    const float* pw    = (const float*)d_in[3];
    const float* ow    = (const float*)d_in[4];
    const int*   edges = (const int*)d_in[5];
    const float* Tlc   = (const float*)d_in[6];
    float* out = (float*)d_out;

    int n = in_sizes[1] / 8;   // N_FRAME - 1
    int half = (n + 1) / 2;
    const int block = 256;
    int grid = (half + block - 1) / block;
    pgo_kernel<<<grid, block, 0, stream>>>(Twc, Tp, To, pw, ow, edges, Tlc,
                                           out, n, half);
}

// Round 6
// 215.517 us; speedup vs baseline: 1.0413x; 1.0413x over previous
//
#include <hip/hip_runtime.h>
#include <math.h>

#define EPSF 1e-6f

typedef float v4f __attribute__((ext_vector_type(4)));
typedef int   v2i __attribute__((ext_vector_type(2)));

struct F3   { float x, y, z; };
struct Quat { float x, y, z, w; };
struct Sim3 { F3 t; Quat q; float s; };

__device__ __forceinline__ F3 cross3(F3 a, F3 b) {
    return { a.y*b.z - a.z*b.y, a.z*b.x - a.x*b.z, a.x*b.y - a.y*b.x };
}

__device__ __forceinline__ F3 quat_rotate(Quat q, F3 v) {
    F3 qv { q.x, q.y, q.z };
    F3 uv  = cross3(qv, v);
    F3 cuv = cross3(qv, uv);
    return { v.x + 2.0f*(q.w*uv.x + cuv.x),
             v.y + 2.0f*(q.w*uv.y + cuv.y),
             v.z + 2.0f*(q.w*uv.z + cuv.z) };
}

__device__ __forceinline__ Quat quat_mul(Quat a, Quat b) {
    return {
        a.w*b.x + a.x*b.w + a.y*b.z - a.z*b.y,
        a.w*b.y - a.x*b.z + a.y*b.w + a.z*b.x,
        a.w*b.z + a.x*b.y - a.y*b.x + a.z*b.w,
        a.w*b.w - a.x*b.x - a.y*b.y - a.z*b.z
    };
}

__device__ __forceinline__ Sim3 sim3_inv(Sim3 T) {
    Quat qi { -T.q.x, -T.q.y, -T.q.z, T.q.w };
    float si = __fdividef(1.0f, T.s);
    F3 r = quat_rotate(qi, T.t);
    return { { -si*r.x, -si*r.y, -si*r.z }, qi, si };
}

__device__ __forceinline__ Sim3 sim3_mul(Sim3 A, Sim3 B) {
    F3 r = quat_rotate(A.q, B.t);
    return { { A.t.x + A.s*r.x, A.t.y + A.s*r.y, A.t.z + A.s*r.z },
             quat_mul(A.q, B.q), A.s * B.s };
}

// rows are 8 floats = 32 B, base 256-B aligned -> v4f-safe.
// ALL loads are plain cached loads this round: rounds 1-5 showed
// dur == hbm_bytes / 3.3 TB/s exactly, and 160 MB of the fetch went
// through nontemporal (L2-bypass) loads -- A/B test: NT loads as the
// rate cap vs a genuine pattern ceiling.
__device__ __forceinline__ Sim3 load_sim3(const float* __restrict__ p) {
    v4f a = *reinterpret_cast<const v4f*>(p);
    v4f b = *reinterpret_cast<const v4f*>(p + 4);
    return { {a.x, a.y, a.z}, {a.w, b.x, b.y, b.z}, b.w };
}

// atan2 for y >= 0 -> [0, pi].  A&S 4.4.49 polynomial, |err| <= 1e-5 rad.
__device__ __forceinline__ float fast_atan2_pos(float y, float x) {
    float ax = fabsf(x);
    float mn = fminf(y, ax);
    float mx = fmaxf(y, ax);
    float t  = __fdividef(mn, mx);
    float s  = t * t;
    float p  = fmaf(s, 0.0208351f, -0.0851330f);
    p = fmaf(s, p,  0.1801410f);
    p = fmaf(s, p, -0.3302995f);
    p = fmaf(s, p,  0.9998660f);
    float r = t * p;
    r = (y > ax)   ? (1.5707963268f - r) : r;
    r = (x < 0.0f) ? (3.1415926536f - r) : r;
    return r;
}

// out[0..2]=tau, out[3..5]=phi, out[6]=sigma — mirrors the jax reference
// branch-for-branch; generic A,B,C path under a wave-uniform branch
// (fallbacks ~never taken for this data).  f32 Cramer + 1 refinement step
// (verified round 4: absmax 0.5 vs 4.88 threshold).
__device__ __forceinline__ void sim3_log(Sim3 T, float out[7]) {
    float qx = T.q.x, qy = T.q.y, qz = T.q.z, qw = T.q.w;
    float nv = sqrtf(qx*qx + qy*qy + qz*qz);
    float theta_r = 2.0f * fast_atan2_pos(nv, qw);
    bool  nv_small = nv < EPSF;
    float fac = nv_small ? 2.0f : __fdividef(theta_r, nv);
    float px = fac*qx, py = fac*qy, pz = fac*qz;
    float sigma = __logf(T.s);
    float theta = nv_small ? 2.0f*nv : theta_r;

    bool sig_small = fabsf(sigma) < EPSF;
    bool th_small  = theta < EPSF;
    float scale = __expf(sigma);
    float A, B, C;
    if (!sig_small && !th_small) {
        float th = theta, sg = sigma;
        float th2 = th*th, sg2 = sg*sg;
        C = __fdividef(scale - 1.0f, sg);
        float sth = __sinf(th), cth = __cosf(th);
        float a = scale * sth;
        float b = scale * cth;
        float c = th2 + sg2;
        float rc = __fdividef(1.0f, c);
        A = __fdividef(fmaf(a, sg, (1.0f - b)*th), th * c);
        B = __fdividef(C - fmaf(b - 1.0f, sg, a*th) * rc, th2);
    } else {
        float sg = sig_small ? 1.0f : sigma;
        float th = th_small  ? 1.0f : theta;
        float th2 = th*th, sg2 = sg*sg;
        C = sig_small ? 1.0f : __fdividef(scale - 1.0f, sg);
        float sth = __sinf(th), cth = __cosf(th);
        float A_ss = th_small ? 0.5f : __fdividef(1.0f - cth, th2);
        float B_ss = th_small ? (1.0f/6.0f) : __fdividef(th - sth, th2 * th);
        float a = scale * sth;
        float b = scale * cth;
        float c = th2 + sg2;
        float rc = __fdividef(1.0f, c);
        float A_g = __fdividef(fmaf(a, sg, (1.0f - b)*th), th * c);
        float B_g = __fdividef(C - fmaf(b - 1.0f, sg, a*th) * rc, th2);
        float A_ts = __fdividef(fmaf(sg - 1.0f, scale, 1.0f), sg2);
        float B_ts = __fdividef(fmaf(scale, fmaf(sg, sg - 2.0f, 2.0f), -2.0f), 2.0f*sg2*sg);
        A = sig_small ? A_ss : (th_small ? A_ts : A_g);
        B = sig_small ? B_ss : (th_small ? B_ts : B_g);
    }

    float P01 = -pz, P02 =  py;
    float P10 =  pz, P12 = -px;
    float P20 = -py, P21 =  px;
    float Q00 = P01*P10 + P02*P20;
    float Q01 = P02*P21;
    float Q02 = P01*P12;
    float Q10 = P12*P20;
    float Q11 = P10*P01 + P12*P21;
    float Q12 = P10*P02;
    float Q20 = P21*P10;
    float Q21 = P20*P01;
    float Q22 = P20*P02 + P21*P12;

    float W00 = C + B*Q00,          W01 = A*P01 + B*Q01, W02 = A*P02 + B*Q02;
    float W10 = A*P10 + B*Q10,      W11 = C + B*Q11,     W12 = A*P12 + B*Q12;
    float W20 = A*P20 + B*Q20,      W21 = A*P21 + B*Q21, W22 = C + B*Q22;

    float c00 = fmaf(W11, W22, -W12*W21);
    float c01 = fmaf(W12, W20, -W10*W22);
    float c02 = fmaf(W10, W21, -W11*W20);
    float a01 = fmaf(W02, W21, -W01*W22);
    float a02 = fmaf(W01, W12, -W02*W11);
    float a11 = fmaf(W00, W22, -W02*W20);
    float a12 = fmaf(W02, W10, -W00*W12);
    float a21 = fmaf(W01, W20, -W00*W21);
    float a22 = fmaf(W00, W11, -W01*W10);
    float det = fmaf(W00, c00, fmaf(W01, c01, W02*c02));
    float idet = __fdividef(1.0f, det);
    float tx = T.t.x, ty = T.t.y, tz = T.t.z;
    float t0 = fmaf(c00, tx, fmaf(a01, ty, a02*tz)) * idet;
    float t1 = fmaf(c01, tx, fmaf(a11, ty, a12*tz)) * idet;
    float t2 = fmaf(c02, tx, fmaf(a21, ty, a22*tz)) * idet;
    float r0 = tx - fmaf(W00, t0, fmaf(W01, t1, W02*t2));
    float r1 = ty - fmaf(W10, t0, fmaf(W11, t1, W12*t2));
    float r2 = tz - fmaf(W20, t0, fmaf(W21, t1, W22*t2));
    t0 = fmaf(fmaf(c00, r0, fmaf(a01, r1, a02*r2)), idet, t0);
    t1 = fmaf(fmaf(c01, r0, fmaf(a11, r1, a12*r2)), idet, t1);
    t2 = fmaf(fmaf(c02, r0, fmaf(a21, r1, a22*r2)), idet, t2);

    out[0] = t0; out[1] = t1; out[2] = t2;
    out[3] = px; out[4] = py; out[5] = pz; out[6] = sigma;
}

// Round-4 structure (1 item/thread, 71.4us best) with NT hints removed.
// Round-5's 2-item variant regressed (79us): per-wave MLP gain was offset
// by halved wave count -- bytes-in-flight conserved, rate stuck at 3.3 TB/s.
__global__ void __launch_bounds__(256) pgo_kernel(
        const float* __restrict__ Twc,
        const float* __restrict__ Tp_inv,
        const float* __restrict__ To_inv,
        const float* __restrict__ pw,
        const float* __restrict__ ow,
        const int*   __restrict__ edges,
        const float* __restrict__ T_lc,
        float*       __restrict__ out,
        int n) {
    int i = blockIdx.x * blockDim.x + threadIdx.x;
    if (i >= n) return;
    size_t i8 = (size_t)i * 8;
    size_t i7 = (size_t)i * 7;

    // gathers first: their latency hides under the prior/odom log chains
    v2i e = *reinterpret_cast<const v2i*>(edges + 2*(size_t)i);
    Sim3 Ta = load_sim3(Twc + (size_t)e.x * 8);
    Sim3 Tb = load_sim3(Twc + (size_t)e.y * 8);
    Sim3 Tl = load_sim3(T_lc + i8);

    Sim3 Ti = load_sim3(Twc + i8);
    Sim3 Tj = load_sim3(Twc + i8 + 8);
    Sim3 Tp = load_sim3(Tp_inv + i8);
    Sim3 To = load_sim3(To_inv + i8);
    float pwv[7], owv[7];
    #pragma unroll
    for (int k = 0; k < 7; ++k) {
        pwv[k] = pw[i7 + k];
        owv[k] = ow[i7 + k];
    }

    Sim3 delta = sim3_mul(sim3_inv(Ti), Tj);

    float acc[7], r[7];
    sim3_log(sim3_mul(delta, Tp), r);
    #pragma unroll
    for (int k = 0; k < 7; ++k) acc[k] = r[k] * pwv[k];

    sim3_log(sim3_mul(delta, To), r);
    #pragma unroll
    for (int k = 0; k < 7; ++k) acc[k] = fmaf(r[k], owv[k], acc[k]);

    sim3_log(sim3_mul(sim3_mul(sim3_inv(Ta), Tb), Tl), r);
    // plain cached stores (round-4: WRITE_SIZE 27.4 MB ~= ideal)
    #pragma unroll
    for (int k = 0; k < 7; ++k)
        out[i7 + k] = acc[k] + r[k];
}

extern "C" void kernel_launch(void* const* d_in, const int* in_sizes, int n_in,
                              void* d_out, int out_size, void* d_ws, size_t ws_size,
                              hipStream_t stream) {
    const float* Twc   = (const float*)d_in[0];
    const float* Tp    = (const float*)d_in[1];
    const float* To    = (const float*)d_in[2];
    const float* pw    = (const float*)d_in[3];
    const float* ow    = (const float*)d_in[4];
    const int*   edges = (const int*)d_in[5];
    const float* Tlc   = (const float*)d_in[6];
    float* out = (float*)d_out;

    int n = in_sizes[1] / 8;  // N_FRAME - 1
    const int block = 256;
    int grid = (n + block - 1) / block;
    pgo_kernel<<<grid, block, 0, stream>>>(Twc, Tp, To, pw, ow, edges, Tlc, out, n);
}